// Round 1
// baseline (1610.660 us; speedup 1.0000x reference)
//
#include <hip/hip_runtime.h>
#include <hip/hip_bf16.h>

#define BB 64
#define SS 1024
#define DD 256
#define ND3 768

typedef __attribute__((ext_vector_type(4))) float f4;

// ---------------------------------------------------------------------------
// Generic 64x64-tile fp32 GEMM: out = A[MxK] @ Bw[KxN] + bias[N]
// EPI==0: plain write to out0 (ld = N)
// EPI==1: QKV split — col n<256 -> out0(Q), <512 -> out1(K), else out2(V), ld=256
// ---------------------------------------------------------------------------
template <int EPI>
__global__ __launch_bounds__(256) void gemm64(
    const float* __restrict__ A, const float* __restrict__ Bw,
    const float* __restrict__ bias, float* __restrict__ out0,
    float* __restrict__ out1, float* __restrict__ out2,
    int M, int N, int K) {
  __shared__ float As[16][68];  // [k][m]
  __shared__ float Bs[16][68];  // [k][n]
  const int t = threadIdx.x;
  const int tx = t & 15, ty = t >> 4;
  const int m0 = blockIdx.y * 64, n0 = blockIdx.x * 64;
  const int r0 = ty * 4, c0 = tx * 4;
  const int arow = t >> 2, ak4 = (t & 3) << 2;   // A tile: 64 rows x 16 k
  const int brow = t >> 4, bc4 = (t & 15) << 2;  // B tile: 16 rows x 64 cols

  float acc[4][4] = {};
  for (int kc = 0; kc < K; kc += 16) {
    __syncthreads();
    f4 av = *(const f4*)&A[(size_t)(m0 + arow) * K + kc + ak4];
    f4 bv = *(const f4*)&Bw[(size_t)(kc + brow) * N + n0 + bc4];
#pragma unroll
    for (int i = 0; i < 4; ++i) As[ak4 + i][arow] = av[i];
    *(f4*)&Bs[brow][bc4] = bv;
    __syncthreads();
#pragma unroll
    for (int kk = 0; kk < 16; ++kk) {
      f4 a = *(const f4*)&As[kk][r0];
      f4 b = *(const f4*)&Bs[kk][c0];
#pragma unroll
      for (int i = 0; i < 4; ++i)
#pragma unroll
        for (int j = 0; j < 4; ++j) acc[i][j] += a[i] * b[j];
    }
  }

  // epilogue
  float* dst = out0;
  int col0, ldo;
  if (EPI == 1) {
    const int sel = n0 >> 8;  // tile lies entirely in one of Q/K/V (64 | 256)
    dst = (sel == 0) ? out0 : ((sel == 1) ? out1 : out2);
    col0 = n0 - (sel << 8) + c0;
    ldo = DD;
  } else {
    col0 = n0 + c0;
    ldo = N;
  }
#pragma unroll
  for (int i = 0; i < 4; ++i) {
    f4 v;
#pragma unroll
    for (int j = 0; j < 4; ++j) v[j] = acc[i][j] + bias[n0 + c0 + j];
    *(f4*)&dst[(size_t)(m0 + r0 + i) * ldo + col0] = v;
  }
}

// ---------------------------------------------------------------------------
// B1: scores tile (64 q-rows x full S cols), exp (no max needed: |s| < ~1),
// causal mask (exact 0), write unnormalized exp to attn region, row sums out.
// grid: (S/64, B)
// ---------------------------------------------------------------------------
__global__ __launch_bounds__(256) void attn_scores(
    const float* __restrict__ Q, const float* __restrict__ Kb,
    float* __restrict__ attn, float* __restrict__ rowsum) {
  __shared__ float Qc[16][68];   // [d][r]
  __shared__ float Kc[16][68];   // [d][c]
  __shared__ float red[64][17];
  const int t = threadIdx.x;
  const int tx = t & 15, ty = t >> 4;
  const int qt = blockIdx.x, b = blockIdx.y;
  const int q0 = qt * 64;
  const int r0 = ty * 4, c0 = tx * 4;
  const int lrow = t >> 2, ld4 = (t & 3) << 2;

  const float* Qbase = Q + ((size_t)b * SS + q0) * DD;
  float* attnb = attn + ((size_t)b * SS + q0) * SS;
  float rs[4] = {0.f, 0.f, 0.f, 0.f};

  for (int kt = 0; kt < 16; ++kt) {
    const int k0 = kt * 64;
    if (kt > qt) {  // fully masked tile: attn entries are exactly 0
      f4 z = {0.f, 0.f, 0.f, 0.f};
#pragma unroll
      for (int i = 0; i < 4; ++i)
        *(f4*)&attnb[(size_t)(r0 + i) * SS + k0 + c0] = z;
      continue;
    }
    const float* Kbase = Kb + ((size_t)b * SS + k0) * DD;
    float acc[4][4] = {};
    for (int dc = 0; dc < DD; dc += 16) {
      __syncthreads();
      f4 qv = *(const f4*)&Qbase[(size_t)lrow * DD + dc + ld4];
      f4 kv = *(const f4*)&Kbase[(size_t)lrow * DD + dc + ld4];
#pragma unroll
      for (int i = 0; i < 4; ++i) {
        Qc[ld4 + i][lrow] = qv[i];
        Kc[ld4 + i][lrow] = kv[i];
      }
      __syncthreads();
#pragma unroll
      for (int dd = 0; dd < 16; ++dd) {
        f4 a = *(const f4*)&Qc[dd][r0];
        f4 bv = *(const f4*)&Kc[dd][c0];
#pragma unroll
        for (int i = 0; i < 4; ++i)
#pragma unroll
          for (int j = 0; j < 4; ++j) acc[i][j] += a[i] * bv[j];
      }
    }
    // mask + exp + write + accumulate row sums
#pragma unroll
    for (int i = 0; i < 4; ++i) {
      const int qg = q0 + r0 + i;
      f4 p;
#pragma unroll
      for (int j = 0; j < 4; ++j) {
        const int kg = k0 + c0 + j;
        const float s = acc[i][j] * 0.0625f;  // 1/sqrt(256)
        const float e = (kg <= qg) ? expf(s) : 0.f;
        p[j] = e;
        rs[i] += e;
      }
      *(f4*)&attnb[(size_t)(r0 + i) * SS + k0 + c0] = p;
    }
  }

  __syncthreads();
#pragma unroll
  for (int i = 0; i < 4; ++i) red[r0 + i][tx] = rs[i];
  __syncthreads();
  if (t < 64) {
    float s = 0.f;
#pragma unroll
    for (int x = 0; x < 16; ++x) s += red[t][x];
    rowsum[(size_t)b * SS + q0 + t] = s;
  }
}

// ---------------------------------------------------------------------------
// B2: normalize attn in place (only non-masked tiles need it; masked are 0),
// and compute out_attn = attn @ V (64 q-rows x 256 d) fused.
// grid: (S/64, B)
// ---------------------------------------------------------------------------
__global__ __launch_bounds__(256) void attn_pv(
    float* __restrict__ attn, const float* __restrict__ V,
    const float* __restrict__ rowsum, float* __restrict__ outa) {
  __shared__ float Ps[64][68];
  __shared__ float Vs[64][68];
  __shared__ float inv[64];
  const int t = threadIdx.x;
  const int tx = t & 15, ty = t >> 4;
  const int qt = blockIdx.x, b = blockIdx.y;
  const int q0 = qt * 64;
  const int r0 = ty * 4;

  if (t < 64) inv[t] = 1.0f / rowsum[(size_t)b * SS + q0 + t];

  float* attnb = attn + ((size_t)b * SS + q0) * SS;
  const float* Vb = V + (size_t)b * SS * DD;
  float acc[4][4][4] = {};  // [cg][i][j]

  for (int kt = 0; kt <= qt; ++kt) {
    const int k0 = kt * 64;
    __syncthreads();  // prev compute done reading Ps/Vs (also inv ready)
#pragma unroll
    for (int rep = 0; rep < 4; ++rep) {
      const int row = rep * 16 + ty;
      const size_t ga = (size_t)row * SS + k0 + tx * 4;
      f4 p = *(const f4*)&attnb[ga];
      p *= inv[row];
      *(f4*)&attnb[ga] = p;        // write normalized attn (final value)
      *(f4*)&Ps[row][tx * 4] = p;
    }
#pragma unroll
    for (int cg = 0; cg < 4; ++cg) {
      __syncthreads();  // Ps ready / prev Vs consumed
#pragma unroll
      for (int rep = 0; rep < 4; ++rep) {
        const int row = rep * 16 + ty;
        f4 v = *(const f4*)&Vb[(size_t)(k0 + row) * DD + cg * 64 + tx * 4];
        *(f4*)&Vs[row][tx * 4] = v;
      }
      __syncthreads();
#pragma unroll 4
      for (int kk = 0; kk < 64; ++kk) {
        f4 bv = *(const f4*)&Vs[kk][tx * 4];
        const float a0 = Ps[r0 + 0][kk];
        const float a1 = Ps[r0 + 1][kk];
        const float a2 = Ps[r0 + 2][kk];
        const float a3 = Ps[r0 + 3][kk];
#pragma unroll
        for (int j = 0; j < 4; ++j) {
          acc[cg][0][j] += a0 * bv[j];
          acc[cg][1][j] += a1 * bv[j];
          acc[cg][2][j] += a2 * bv[j];
          acc[cg][3][j] += a3 * bv[j];
        }
      }
    }
  }

#pragma unroll
  for (int cg = 0; cg < 4; ++cg)
#pragma unroll
    for (int i = 0; i < 4; ++i) {
      f4 o = {acc[cg][i][0], acc[cg][i][1], acc[cg][i][2], acc[cg][i][3]};
      *(f4*)&outa[((size_t)b * SS + q0 + r0 + i) * DD + cg * 64 + tx * 4] = o;
    }
}

// ---------------------------------------------------------------------------
extern "C" void kernel_launch(void* const* d_in, const int* in_sizes, int n_in,
                              void* d_out, int out_size, void* d_ws,
                              size_t ws_size, hipStream_t stream) {
  const float* x    = (const float*)d_in[0];
  const float* Wqkv = (const float*)d_in[1];
  const float* bqkv = (const float*)d_in[2];
  const float* Wout = (const float*)d_in[3];
  const float* bout = (const float*)d_in[4];

  float* out  = (float*)d_out;                       // [B,S,D]
  float* attn = out + (size_t)BB * SS * DD;          // [B,1,S,S]

  float* ws = (float*)d_ws;
  float* Qb = ws;                                    // [B*S, D]
  float* Kb = ws + (size_t)BB * SS * DD;             // [B*S, D]
  float* Vb = ws + 2 * (size_t)BB * SS * DD;         // [B*S, D]
  float* rowsum = ws + 3 * (size_t)BB * SS * DD;     // [B*S]
  float* outa = Qb;  // out_attn aliases Q (Q dead after attn_scores)

  dim3 thr(256);
  // 1. QKV projection, split into Q/K/V
  gemm64<1><<<dim3(ND3 / 64, BB * SS / 64), thr, 0, stream>>>(
      x, Wqkv, bqkv, Qb, Kb, Vb, BB * SS, ND3, DD);
  // 2. scores + exp + rowsum (unnormalized attn written)
  attn_scores<<<dim3(SS / 64, BB), thr, 0, stream>>>(Qb, Kb, attn, rowsum);
  // 3. normalize attn in place + PV
  attn_pv<<<dim3(SS / 64, BB), thr, 0, stream>>>(attn, Vb, rowsum, outa);
  // 4. output projection
  gemm64<0><<<dim3(DD / 64, BB * SS / 64), thr, 0, stream>>>(
      outa, Wout, bout, out, nullptr, nullptr, BB * SS, DD, DD);
}

// Round 2
// 396.129 us; speedup vs baseline: 4.0660x; 4.0660x over previous
//
#include <hip/hip_runtime.h>
#include <hip/hip_bf16.h>

#define BB 64
#define SS 1024
#define DDIM 256

typedef unsigned short u16;
typedef __attribute__((ext_vector_type(4))) float f4;
typedef __attribute__((ext_vector_type(8))) short bf16x8;
typedef __attribute__((ext_vector_type(4))) short bf16x4;
typedef __attribute__((ext_vector_type(4))) float f32x4;

__device__ inline u16 f2b(float f) {
  unsigned int u = __float_as_uint(f);
  unsigned int r = (u + 0x7fffu + ((u >> 16) & 1u)) >> 16;
  return (u16)r;
}

// ---------------------------------------------------------------------------
// Cast x (f32 -> bf16), vectorized 8/thread, grid-stride.
// ---------------------------------------------------------------------------
__global__ __launch_bounds__(256) void cast_x(const float* __restrict__ x,
                                              u16* __restrict__ xb, int n8) {
  int i = blockIdx.x * 256 + threadIdx.x;
  const int stride = gridDim.x * 256;
  for (; i < n8; i += stride) {
    f4 a = ((const f4*)x)[2 * i];
    f4 b = ((const f4*)x)[2 * i + 1];
    bf16x8 o;
    o[0] = f2b(a[0]); o[1] = f2b(a[1]); o[2] = f2b(a[2]); o[3] = f2b(a[3]);
    o[4] = f2b(b[0]); o[5] = f2b(b[1]); o[6] = f2b(b[2]); o[7] = f2b(b[3]);
    ((bf16x8*)xb)[i] = o;
  }
}

// Cast + transpose W_qkv [256][768] -> [768][256], W_out [256][256] -> [256][256]
__global__ __launch_bounds__(256) void cast_w(const float* __restrict__ Wqkv,
                                              const float* __restrict__ Wout,
                                              u16* __restrict__ Wqkvt,
                                              u16* __restrict__ Woutt) {
  int t = blockIdx.x * 256 + threadIdx.x;
  if (t < 256 * 768) {
    int k = t / 768, n = t % 768;
    Wqkvt[n * 256 + k] = f2b(Wqkv[t]);
  }
  if (t < 256 * 256) {
    int k = t / 256, n = t % 256;
    Woutt[n * 256 + k] = f2b(Wout[t]);
  }
}

// ---------------------------------------------------------------------------
// MFMA GEMM: C[M x N] = A[M x 256] * B[256 x N] + bias, A bf16 row-major,
// Bt = B^T bf16 [N][256]. 128x128 tile, 4 waves (each 64x64), BK=64,
// reg-staged LDS with XOR chunk swizzle (conflict-free ds_read_b128).
// EPI 0: write f32 to outF (ld=256).
// EPI 1: QKV split: n<256 -> Qb bf16, n<512 -> Kb bf16, else Vt[b][d][s] bf16.
// ---------------------------------------------------------------------------
template <int EPI>
__global__ __launch_bounds__(256) void gemm_mfma(
    const u16* __restrict__ A, const u16* __restrict__ Bt,
    const float* __restrict__ bias, float* __restrict__ outF,
    u16* __restrict__ Qb, u16* __restrict__ Kb, u16* __restrict__ Vt) {
  __shared__ u16 As[128 * 64];
  __shared__ u16 Bs[128 * 64];
  const int t = threadIdx.x;
  const int w = t >> 6, l = t & 63;
  const int lr = l & 15, lg = l >> 4;
  const int m0 = blockIdx.y * 128, n0 = blockIdx.x * 128;
  const int wm = (w >> 1) * 64, wn = (w & 1) * 64;

  f32x4 acc[4][4] = {};

  for (int k0 = 0; k0 < 256; k0 += 64) {
    __syncthreads();
#pragma unroll
    for (int j = 0; j < 4; ++j) {
      int id = t + j * 256;
      int row = id >> 3, c = id & 7;
      f4 va = *(const f4*)&A[(size_t)(m0 + row) * 256 + k0 + c * 8];
      *(f4*)&As[row * 64 + ((c ^ (row & 7)) * 8)] = va;
      f4 vb = *(const f4*)&Bt[(size_t)(n0 + row) * 256 + k0 + c * 8];
      *(f4*)&Bs[row * 64 + ((c ^ (row & 7)) * 8)] = vb;
    }
    __syncthreads();
#pragma unroll
    for (int kc = 0; kc < 2; ++kc) {
      bf16x8 af[4], bfr[4];
#pragma unroll
      for (int f = 0; f < 4; ++f) {
        int ar = wm + f * 16 + lr;
        af[f] = *(const bf16x8*)&As[ar * 64 + (((kc * 4 + lg) ^ (ar & 7)) * 8)];
        int br = wn + f * 16 + lr;
        bfr[f] = *(const bf16x8*)&Bs[br * 64 + (((kc * 4 + lg) ^ (br & 7)) * 8)];
      }
#pragma unroll
      for (int i = 0; i < 4; ++i)
#pragma unroll
        for (int jn = 0; jn < 4; ++jn)
          acc[i][jn] = __builtin_amdgcn_mfma_f32_16x16x32_bf16(
              af[i], bfr[jn], acc[i][jn], 0, 0, 0);
    }
  }

  // Epilogue. C frag: col = lr, row = lg*4 + r.
#pragma unroll
  for (int i = 0; i < 4; ++i) {
    const int mbase = m0 + wm + i * 16 + lg * 4;
#pragma unroll
    for (int jn = 0; jn < 4; ++jn) {
      const int n = n0 + wn + jn * 16 + lr;
      const float bv = bias[n];
      if (EPI == 0) {
#pragma unroll
        for (int r = 0; r < 4; ++r)
          outF[(size_t)(mbase + r) * 256 + n] = acc[i][jn][r] + bv;
      } else {
        if (n < 256) {
#pragma unroll
          for (int r = 0; r < 4; ++r)
            Qb[(size_t)(mbase + r) * 256 + n] = f2b(acc[i][jn][r] + bv);
        } else if (n < 512) {
#pragma unroll
          for (int r = 0; r < 4; ++r)
            Kb[(size_t)(mbase + r) * 256 + (n - 256)] = f2b(acc[i][jn][r] + bv);
        } else {
          const int d = n - 512;
          const int b = mbase >> 10, sl = mbase & 1023;
          bf16x4 pk;
#pragma unroll
          for (int r = 0; r < 4; ++r) pk[r] = f2b(acc[i][jn][r] + bv);
          *(bf16x4*)&Vt[((size_t)b * 256 + d) * 1024 + sl] = pk;
        }
      }
    }
  }
}

// ---------------------------------------------------------------------------
// Fused attention: per block = one (b, q-tile of 64). 4 waves x 16 q-rows.
// Pass A: S = QK^T (MFMA) + exp -> rowsums only.
// Pass B: recompute S, normalize, write attn f32 once, P->LDS (bf16),
//         PV MFMA with pre-transposed V tile. Zero-write masked tiles.
// ---------------------------------------------------------------------------
__global__ __launch_bounds__(256) void attn_fused(
    const u16* __restrict__ Qg, const u16* __restrict__ Kg,
    const u16* __restrict__ Vtg, float* __restrict__ attn,
    u16* __restrict__ outa) {
  __shared__ u16 Ks[64 * 256];   // swizzled [s][d]
  __shared__ u16 Vs[256 * 64];   // swizzled [d][s]
  __shared__ u16 Ps[4][16 * 80]; // per-wave P tile [q][s], row pad 80
  __shared__ float rs[64];
  __shared__ float inv[64];

  const int t = threadIdx.x;
  const int w = t >> 6, l = t & 63;
  const int lr = l & 15, lg = l >> 4;
  const int qt = blockIdx.x, b = blockIdx.y;
  const int q0 = qt * 64;
  const int qwl = w * 16;  // wave's q offset in tile

  // Q A-frags in registers: lane: q = qwl+lr, k(d) = f*32 + lg*8 + j
  bf16x8 qf[8];
  {
    const u16* qbase = Qg + ((size_t)(b * 1024 + q0 + qwl + lr)) * 256;
#pragma unroll
    for (int f = 0; f < 8; ++f) qf[f] = *(const bf16x8*)&qbase[f * 32 + lg * 8];
  }

  float rowacc[4] = {0.f, 0.f, 0.f, 0.f};

  // ---- PASS A: rowsums ----
  for (int kt = 0; kt <= qt; ++kt) {
    __syncthreads();
    const u16* kg = Kg + ((size_t)(b * 1024 + kt * 64)) * 256;
#pragma unroll
    for (int j = 0; j < 8; ++j) {
      int id = t + j * 256;
      int row = id >> 5, c = id & 31;
      f4 v = *(const f4*)&kg[(size_t)row * 256 + c * 8];
      *(f4*)&Ks[row * 256 + ((c ^ (row & 7)) * 8)] = v;
    }
    __syncthreads();
#pragma unroll
    for (int sf = 0; sf < 4; ++sf) {
      f32x4 sacc = {0.f, 0.f, 0.f, 0.f};
      const int srow = sf * 16 + lr;
#pragma unroll
      for (int kc = 0; kc < 8; ++kc) {
        bf16x8 bfr = *(const bf16x8*)&Ks[srow * 256 + (((kc * 4 + lg) ^ (srow & 7)) * 8)];
        sacc = __builtin_amdgcn_mfma_f32_16x16x32_bf16(qf[kc], bfr, sacc, 0, 0, 0);
      }
      const int scol = kt * 64 + sf * 16 + lr;
      const int qrow = q0 + qwl + lg * 4;
#pragma unroll
      for (int r = 0; r < 4; ++r) {
        float e = (scol <= qrow + r) ? __expf(sacc[r] * 0.0625f) : 0.f;
        rowacc[r] += e;
      }
    }
  }
#pragma unroll
  for (int m = 1; m < 16; m <<= 1)
#pragma unroll
    for (int r = 0; r < 4; ++r) rowacc[r] += __shfl_xor(rowacc[r], m, 64);
  if (lr == 0) {
#pragma unroll
    for (int r = 0; r < 4; ++r) rs[qwl + lg * 4 + r] = rowacc[r];
  }
  __syncthreads();
  if (t < 64) inv[t] = 1.0f / rs[t];

  // ---- PASS B ----
  float* attnb = attn + ((size_t)(b * 1024 + q0)) * 1024;
  f32x4 oacc[16];
#pragma unroll
  for (int f = 0; f < 16; ++f) oacc[f] = (f32x4){0.f, 0.f, 0.f, 0.f};

  for (int kt = 0; kt < 16; ++kt) {
    if (kt <= qt) {
      __syncthreads();
      const u16* kg = Kg + ((size_t)(b * 1024 + kt * 64)) * 256;
#pragma unroll
      for (int j = 0; j < 8; ++j) {
        int id = t + j * 256;
        int row = id >> 5, c = id & 31;
        f4 v = *(const f4*)&kg[(size_t)row * 256 + c * 8];
        *(f4*)&Ks[row * 256 + ((c ^ (row & 7)) * 8)] = v;
      }
      const u16* vg = Vtg + (size_t)b * 256 * 1024 + kt * 64;
#pragma unroll
      for (int j = 0; j < 8; ++j) {
        int id = t + j * 256;
        int row = id >> 3, c = id & 7;
        f4 v = *(const f4*)&vg[(size_t)row * 1024 + c * 8];
        *(f4*)&Vs[row * 64 + ((c ^ (row & 7)) * 8)] = v;
      }
      __syncthreads();
      // S recompute + normalize + attn write + P stash
#pragma unroll
      for (int sf = 0; sf < 4; ++sf) {
        f32x4 sacc = {0.f, 0.f, 0.f, 0.f};
        const int srow = sf * 16 + lr;
#pragma unroll
        for (int kc = 0; kc < 8; ++kc) {
          bf16x8 bfr = *(const bf16x8*)&Ks[srow * 256 + (((kc * 4 + lg) ^ (srow & 7)) * 8)];
          sacc = __builtin_amdgcn_mfma_f32_16x16x32_bf16(qf[kc], bfr, sacc, 0, 0, 0);
        }
        const int scol_l = sf * 16 + lr;
        const int scol = kt * 64 + scol_l;
#pragma unroll
        for (int r = 0; r < 4; ++r) {
          const int il = qwl + lg * 4 + r;
          const int qrow = q0 + il;
          float e = (scol <= qrow) ? __expf(sacc[r] * 0.0625f) : 0.f;
          float p = e * inv[il];
          attnb[(size_t)il * 1024 + scol] = p;
          Ps[w][(lg * 4 + r) * 80 + scol_l] = f2b(p);
        }
      }
      // PV: A-frags of P (wave-local LDS), B-frags of V (pre-transposed)
      bf16x8 pa[2];
#pragma unroll
      for (int kc = 0; kc < 2; ++kc)
        pa[kc] = *(const bf16x8*)&Ps[w][lr * 80 + kc * 32 + lg * 8];
#pragma unroll
      for (int df = 0; df < 16; ++df) {
        const int drow = df * 16 + lr;
#pragma unroll
        for (int kc = 0; kc < 2; ++kc) {
          bf16x8 bfr = *(const bf16x8*)&Vs[drow * 64 + (((kc * 4 + lg) ^ (drow & 7)) * 8)];
          oacc[df] = __builtin_amdgcn_mfma_f32_16x16x32_bf16(pa[kc], bfr, oacc[df], 0, 0, 0);
        }
      }
    } else {
      // masked tile: exact zeros
#pragma unroll
      for (int j = 0; j < 4; ++j) {
        int id = t + j * 256;
        int row = id >> 4, c = id & 15;
        f4 z = {0.f, 0.f, 0.f, 0.f};
        *(f4*)&attnb[(size_t)row * 1024 + kt * 64 + c * 4] = z;
      }
    }
  }

  // O write (already-normalized P was used, so no rescale of oacc needed)
#pragma unroll
  for (int df = 0; df < 16; ++df) {
#pragma unroll
    for (int r = 0; r < 4; ++r) {
      const int il = qwl + lg * 4 + r;
      outa[((size_t)(b * 1024 + q0 + il)) * 256 + df * 16 + lr] = f2b(oacc[df][r]);
    }
  }
}

// ---------------------------------------------------------------------------
extern "C" void kernel_launch(void* const* d_in, const int* in_sizes, int n_in,
                              void* d_out, int out_size, void* d_ws,
                              size_t ws_size, hipStream_t stream) {
  const float* x    = (const float*)d_in[0];
  const float* Wqkv = (const float*)d_in[1];
  const float* bqkv = (const float*)d_in[2];
  const float* Wout = (const float*)d_in[3];
  const float* bout = (const float*)d_in[4];

  float* out  = (float*)d_out;                     // [B,S,D] f32
  float* attn = out + (size_t)BB * SS * DDIM;      // [B,1,S,S] f32

  const size_t NTOK = (size_t)BB * SS;             // 65536
  u16* ws = (u16*)d_ws;
  u16* xb    = ws;                                 // [NTOK][256] bf16
  u16* Qb    = xb + NTOK * DDIM;
  u16* Kb    = Qb + NTOK * DDIM;
  u16* Vt    = Kb + NTOK * DDIM;                   // [B][256][1024] bf16
  u16* outa  = Vt + NTOK * DDIM;
  u16* Wqkvt = outa + NTOK * DDIM;                 // [768][256]
  u16* Woutt = Wqkvt + 768 * 256;                  // [256][256]

  cast_x<<<2048, 256, 0, stream>>>(x, xb, (int)(NTOK * DDIM / 8));
  cast_w<<<768, 256, 0, stream>>>(Wqkv, Wout, Wqkvt, Woutt);

  gemm_mfma<1><<<dim3(6, 512), 256, 0, stream>>>(xb, Wqkvt, bqkv, nullptr, Qb,
                                                 Kb, Vt);
  attn_fused<<<dim3(16, BB), 256, 0, stream>>>(Qb, Kb, Vt, attn, outa);
  gemm_mfma<0><<<dim3(2, 512), 256, 0, stream>>>(outa, Woutt, bout, out,
                                                 nullptr, nullptr, nullptr);
}